// Round 7
// baseline (391.967 us; speedup 1.0000x reference)
//
#include <hip/hip_runtime.h>

// Fused attention block (b=2, n=2048, dim=256, heads=8, inner=16384, d_head=2048)
// LOW-RANK FACTORIZATION (d_head >> d_model):
//   S_h  = xn M_h xn^T  (M_h = Wq_h^T Wk_h : 256x256)
//   Zt_h = N_h xn^T     (N_h = Wo_h Wv_h   : 256x256)
// Q,K,V,O never materialize; 77 GF total.
// SOFTMAX IS FUSED INTO THE GEMMS (no max-subtraction; S_rms~0.36 -> exp safe):
//   S-GEMM epilogue:  E = exp(S) stored bf16 + atomic row-sums l[row] (fp32)
//   out-GEMM epilogue: scale by 1/l[row]  (linear -> split-K/atomic safe)
// Pipeline: tcast Wq/Wk/Wv ; cast Wo ; LN ; Mt_h = wkt wqt^T ; N_h = wo wvt^T ;
//   Y = xn Mt^T ; Zt = N xn^T ; E = exp(Y_h xn^T) + rowsums ; out += (E/l) Zt.
// All GEMMs B^T-form, m97 recipe: 128x128 tile, BK=32, mfma 16x16x32 bf16,
// global_load_lds width=16, 2-barrier K-loop.  3rd grid factor kc for split-K.

typedef unsigned short u16;
typedef unsigned int u32;
typedef __bf16 bf16x8 __attribute__((ext_vector_type(8)));
typedef float f32x4 __attribute__((ext_vector_type(4)));

__device__ __forceinline__ u16 f2bf(float f) {
    u32 u = __builtin_bit_cast(u32, f);
    u += 0x7fffu + ((u >> 16) & 1u);   // RNE; inputs finite
    return (u16)(u >> 16);
}

#define GLDS16(G, L)                                                                  \
    __builtin_amdgcn_global_load_lds((const __attribute__((address_space(1))) u32*)(G), \
                                     (__attribute__((address_space(3))) u32*)(L), 16, 0, 0)

// ---------------------------------------------------------------------------
// B^T GEMM: C[m,n] (+)= sum_k A[m,k] * B[n,k].  M,N multiples of 128, K of 32.
// blockIdx.z = ((kc*NB)+zb)*H + zh : zh=head, zb=batch, kc=split-K chunk.
// EXPSUM: epilogue exp + atomic row-sums into lrow.  SCALEL: scale by 1/lrow.
// ---------------------------------------------------------------------------
template <typename OutT, bool ATOMIC, bool EXPSUM, bool SCALEL>
__global__ void __launch_bounds__(256, 4) gemm_bt(
    const u16* __restrict__ A, const u16* __restrict__ B, OutT* __restrict__ C,
    int K, int lda, int ldb, int ldc,
    long sAh, long sAb, long sBh, long sBb, long sCh, long sCb,
    int H, int NB, long ksA, long ksB,
    float* __restrict__ lrow, long sLh, long sLb)
{
    __shared__ u16 ldsA[128 * 32];
    __shared__ u16 ldsB[128 * 32];

    const int z = blockIdx.z;
    const int zh = z % H;
    const int zq = z / H;
    const int zb = zq % NB;
    const int kc = zq / NB;
    A += (size_t)zh * sAh + (size_t)zb * sAb + (size_t)kc * ksA;
    B += (size_t)zh * sBh + (size_t)zb * sBb + (size_t)kc * ksB;
    C += (size_t)zh * sCh + (size_t)zb * sCb;
    if (EXPSUM || SCALEL) lrow += (size_t)zh * sLh + (size_t)zb * sLb;

    const int bm = blockIdx.y * 128;
    const int bn = blockIdx.x * 128;
    const int t = threadIdx.x;
    const int w = t >> 6, l = t & 63;
    const int wm = w >> 1, wn = w & 1;          // 2x2 waves, each 64x64
    const int lr = l & 15, lk = l >> 4;         // frag row / k-chunk
    const int sw = lk ^ ((lr >> 1) & 3);        // XOR-swizzled slot (2-way LDS = free)

    // staging: 512 chunks of 16B per tile; thread t covers chunks t and 256+t.
    // LDS slot s of row m holds global k-chunk c = s ^ ((m>>1)&3).
    const int m0 = t >> 2, s0 = t & 3;
    const int c0 = s0 ^ ((m0 >> 1) & 3);
    const int m1 = 64 + m0;
    const int c1 = s0 ^ ((m1 >> 1) & 3);

    const u16* gA0 = A + (size_t)(bm + m0) * lda + c0 * 8;
    const u16* gA1 = A + (size_t)(bm + m1) * lda + c1 * 8;
    const u16* gB0 = B + (size_t)(bn + m0) * ldb + c0 * 8;
    const u16* gB1 = B + (size_t)(bn + m1) * ldb + c1 * 8;
    u16* lA0 = &ldsA[(t & ~63) * 8];            // wave-uniform base; HW adds lane*16B
    u16* lA1 = &ldsA[(256 + (t & ~63)) * 8];
    u16* lB0 = &ldsB[(t & ~63) * 8];
    u16* lB1 = &ldsB[(256 + (t & ~63)) * 8];

    f32x4 acc[4][4];
#pragma unroll
    for (int i = 0; i < 4; ++i)
#pragma unroll
        for (int j = 0; j < 4; ++j)
            acc[i][j] = f32x4{0.f, 0.f, 0.f, 0.f};

    const int nk = K >> 5;
    for (int kt = 0; kt < nk; ++kt) {
        __syncthreads();                         // protect LDS from prev iter's readers
        GLDS16(gA0, lA0); GLDS16(gA1, lA1);
        GLDS16(gB0, lB0); GLDS16(gB1, lB1);
        gA0 += 32; gA1 += 32; gB0 += 32; gB1 += 32;
        __syncthreads();                         // drains vmcnt -> tile staged

        bf16x8 av[4], bv[4];
#pragma unroll
        for (int i = 0; i < 4; ++i) {
            av[i] = *(const bf16x8*)&ldsA[(wm * 64 + i * 16 + lr) * 32 + sw * 8];
            bv[i] = *(const bf16x8*)&ldsB[(wn * 64 + i * 16 + lr) * 32 + sw * 8];
        }
#pragma unroll
        for (int i = 0; i < 4; ++i)
#pragma unroll
            for (int j = 0; j < 4; ++j)
                acc[i][j] = __builtin_amdgcn_mfma_f32_16x16x32_bf16(av[i], bv[j], acc[i][j], 0, 0, 0);
    }

    if (EXPSUM) {
        // exp in place, then per-row partial sums (this wave covers cols wn*64..+63)
#pragma unroll
        for (int i = 0; i < 4; ++i)
#pragma unroll
            for (int j = 0; j < 4; ++j)
#pragma unroll
                for (int r = 0; r < 4; ++r)
                    acc[i][j][r] = __expf(acc[i][j][r]);
#pragma unroll
        for (int i = 0; i < 4; ++i)
#pragma unroll
            for (int r = 0; r < 4; ++r) {
                float s = acc[i][0][r] + acc[i][1][r] + acc[i][2][r] + acc[i][3][r];
                s += __shfl_xor(s, 1, 64);
                s += __shfl_xor(s, 2, 64);
                s += __shfl_xor(s, 4, 64);
                s += __shfl_xor(s, 8, 64);       // sum over the 16 lanes of this lk group
                if (lr == 0)
                    atomicAdd(&lrow[bm + wm * 64 + i * 16 + lk * 4 + r], s);
            }
    }

    // C/D layout (m89-verified): col = lane&15, row = (lane>>4)*4 + reg
#pragma unroll
    for (int i = 0; i < 4; ++i) {
        const int row0 = bm + wm * 64 + i * 16 + lk * 4;
        float4 linv;
        if (SCALEL) linv = *(const float4*)&lrow[row0];
#pragma unroll
        for (int j = 0; j < 4; ++j) {
            const int col = bn + wn * 64 + j * 16 + lr;
#pragma unroll
            for (int r = 0; r < 4; ++r) {
                const size_t idx = (size_t)(row0 + r) * ldc + col;
                float v = acc[i][j][r];
                if (SCALEL) v /= (&linv.x)[r];
                if constexpr (ATOMIC) {
                    atomicAdd(&C[idx], v);
                } else if constexpr (sizeof(OutT) == 2) {
                    C[idx] = (OutT)f2bf(v);
                } else {
                    C[idx] = (OutT)v;
                }
            }
        }
    }
}

// ---------------------------------------------------------------------------
// Transposed cast: src fp32 [8][2048][256] -> dst bf16 [8][256][2048],
// dst[h][a][d] = src[h][d][a]*scale.  64x64 tiles via LDS (66-pad: 2-way = free).
// ---------------------------------------------------------------------------
__global__ void __launch_bounds__(256) tcast_kernel(const float* __restrict__ src,
                                                    u16* __restrict__ dst, float scale)
{
    __shared__ u16 tile[64][66];
    const int h = blockIdx.z;
    const int d0 = blockIdx.x * 64;
    const int a0 = blockIdx.y * 64;
    const int t = threadIdx.x;
    const int c = t & 63, r0 = t >> 6;
#pragma unroll
    for (int rr = 0; rr < 16; ++rr) {
        const int r = r0 + rr * 4;
        tile[r][c] = f2bf(src[((size_t)h * 2048 + d0 + r) * 256 + a0 + c] * scale);
    }
    __syncthreads();
#pragma unroll
    for (int rr = 0; rr < 16; ++rr) {
        const int r = r0 + rr * 4;
        dst[((size_t)h * 256 + a0 + r) * 2048 + d0 + c] = tile[c][r];
    }
}

// ---------------------------------------------------------------------------
// LayerNorm over dim=256, out = xn*(gamma+1) in bf16. One wave per row.
// ---------------------------------------------------------------------------
__global__ void __launch_bounds__(64) ln_kernel(const float* __restrict__ x,
                                                const float* __restrict__ g,
                                                u16* __restrict__ xn)
{
    const size_t row = blockIdx.x;
    const int l = threadIdx.x;
    const float4 v = ((const float4*)(x + row * 256))[l];
    float s = v.x + v.y + v.z + v.w;
    float q = v.x * v.x + v.y * v.y + v.z * v.z + v.w * v.w;
#pragma unroll
    for (int o = 32; o > 0; o >>= 1) {
        s += __shfl_xor(s, o, 64);
        q += __shfl_xor(q, o, 64);
    }
    const float mu = s * (1.0f / 256.0f);
    const float var = q * (1.0f / 256.0f) - mu * mu;
    const float rs = rsqrtf(var + 1e-5f);
    const float4 gg = ((const float4*)g)[l];
    ushort4 o4;
    o4.x = f2bf((v.x - mu) * rs * (gg.x + 1.0f));
    o4.y = f2bf((v.y - mu) * rs * (gg.y + 1.0f));
    o4.z = f2bf((v.z - mu) * rs * (gg.z + 1.0f));
    o4.w = f2bf((v.w - mu) * rs * (gg.w + 1.0f));
    ((ushort4*)(xn + row * 256))[l] = o4;
}

// fp32 -> bf16 cast (plain)
__global__ void __launch_bounds__(256) cast_bf16_kernel(const float* __restrict__ src,
                                                        u16* __restrict__ dst, float scale)
{
    const size_t i = (size_t)blockIdx.x * 256 + threadIdx.x;
    const float4 v = ((const float4*)src)[i];
    ushort4 o4;
    o4.x = f2bf(v.x * scale);
    o4.y = f2bf(v.y * scale);
    o4.z = f2bf(v.z * scale);
    o4.w = f2bf(v.w * scale);
    ((ushort4*)dst)[i] = o4;
}

extern "C" void kernel_launch(void* const* d_in, const int* in_sizes, int n_in,
                              void* d_out, int out_size, void* d_ws, size_t ws_size,
                              hipStream_t stream)
{
    (void)in_sizes; (void)n_in;
    const float* x     = (const float*)d_in[0];
    const float* gamma = (const float*)d_in[1];
    const float* Wq    = (const float*)d_in[2];
    const float* Wk    = (const float*)d_in[3];
    const float* Wv    = (const float*)d_in[4];
    const float* Wo    = (const float*)d_in[5];
    float* out = (float*)d_out;

    char* ws = (char*)d_ws;
    const size_t MB = 1048576;
    u16* wqt = (u16*)(ws);             // [8][256][2048] bf16, 8 MB (SCALE folded)
    u16* wkt = (u16*)(ws + 8 * MB);    // 8 MB
    u16* wvt = (u16*)(ws + 16 * MB);   // 8 MB
    u16* wo  = (u16*)(ws + 24 * MB);   // [256][16384] bf16, 8 MB
    u16* xn  = (u16*)(ws + 32 * MB);   // [4096][256] bf16, 2 MB
    u16* Mt  = (u16*)(ws + 34 * MB);   // [8*256][256] bf16: Mt_h = (Wq_h^T Wk_h)^T
    u16* Nb  = (u16*)(ws + 35 * MB);   // [8*256][256] bf16, 1 MB
    u16* Y   = (u16*)(ws + 36 * MB);   // [4096][2048] bf16, 16 MB
    u16* Zt  = (u16*)(ws + 52 * MB);   // [2][2048][2048] bf16, 16 MB
    float* lrow = (float*)(ws + 68 * MB); // [8][2][2048] fp32 row-sums, 128 KB
    u16* S   = (u16*)(ws + 69 * MB);   // E = exp(S): [gs][2][2048][2048] bf16
    const size_t BASE2 = 69 * MB;

    // largest head-chunk gs in {8,4,2,1} whose E buffer fits
    int gs = 1;
    if (ws_size >= BASE2 + 8 * 16 * MB)      gs = 8;
    else if (ws_size >= BASE2 + 4 * 16 * MB) gs = 4;
    else if (ws_size >= BASE2 + 2 * 16 * MB) gs = 2;

    hipMemsetAsync(d_out, 0, (size_t)out_size * sizeof(float), stream);  // atomic accum
    hipMemsetAsync(lrow, 0, 32768 * sizeof(float), stream);              // row-sum accum

    tcast_kernel<<<dim3(32, 4, 8), 256, 0, stream>>>(Wq, wqt, 0.125f);  // SCALE folded
    tcast_kernel<<<dim3(32, 4, 8), 256, 0, stream>>>(Wk, wkt, 1.0f);
    tcast_kernel<<<dim3(32, 4, 8), 256, 0, stream>>>(Wv, wvt, 1.0f);
    cast_bf16_kernel<<<4096, 256, 0, stream>>>(Wo, wo, 1.0f);
    ln_kernel<<<4096, 64, 0, stream>>>(x, gamma, xn);

    // Mt_h[a,c] = sum_e wkt_h[a,e]*wqt_h[c,e] = M_h[c,a] : 256x256, K=2048, z=head
    gemm_bt<u16, false, false, false><<<dim3(2, 2, 8), 256, 0, stream>>>(
        wkt, wqt, Mt, 2048, 2048, 2048, 256,
        524288L, 0, 524288L, 0, 65536L, 0, 8, 1, 0, 0, nullptr, 0, 0);

    // N_h[d',a] = sum_e Wo[d', h*2048+e]*wvt_h[a,e] : 256x256, K=2048, z=head
    gemm_bt<u16, false, false, false><<<dim3(2, 2, 8), 256, 0, stream>>>(
        wo, wvt, Nb, 2048, 16384, 2048, 256,
        2048L, 0, 524288L, 0, 65536L, 0, 8, 1, 0, 0, nullptr, 0, 0);

    // Y[t, h*256+a] = sum_c xn[t,c] * Mt[h*256+a, c]
    gemm_bt<u16, false, false, false><<<dim3(16, 32, 1), 256, 0, stream>>>(
        xn, Mt, Y, 256, 256, 256, 2048,
        0, 0, 0, 0, 0, 0, 1, 1, 0, 0, nullptr, 0, 0);

    // Zt[b][h*256+d', j] = sum_a N[h*256+d', a] * xn[b*2048+j, a] : K=256, z=b
    gemm_bt<u16, false, false, false><<<dim3(16, 16, 2), 256, 0, stream>>>(
        Nb, xn, Zt, 256, 256, 256, 2048,
        0, 0, 0, 524288L, 0, 4194304L, 1, 2, 0, 0, nullptr, 0, 0);

    for (int ci = 0; ci < 8 / gs; ++ci) {
        float* lci = lrow + (size_t)ci * gs * 4096;

        // E[hh][b][i,j] = exp( sum_a Y[b*2048+i,(ci*gs+hh)*256+a] * xn[b*2048+j,a] )
        // + atomic row-sums into lrow.  K=256, z: zh=hh (H=gs), zb=b (NB=2).
        gemm_bt<u16, false, true, false><<<dim3(16, 16, 2 * gs), 256, 0, stream>>>(
            Y + (size_t)ci * gs * 256, xn, S, 256, 2048, 256, 2048,
            256L, 4194304L, 0, 524288L, 8388608L, 4194304L,
            gs, 2, 0, 0, lci, 4096L, 2048L);

        // out[b*2048+i, d'] += sum_j (E/l)[hh][b][i,j] * Zt[b][(ci*gs+hh)*256+d', j]
        // K=2048 split-K x2 (kc): grid z = 2*gs*2.  fp32 atomic, scaled by 1/l.
        gemm_bt<float, true, false, true><<<dim3(2, 16, 4 * gs), 256, 0, stream>>>(
            S, Zt + (size_t)ci * gs * 524288, out, 1024, 2048, 2048, 256,
            8388608L, 4194304L, 524288L, 4194304L, 0L, 524288L,
            gs, 2, 1024L, 1024L, lci, 4096L, 2048L);
    }
}

// Round 8
// 340.820 us; speedup vs baseline: 1.1501x; 1.1501x over previous
//
#include <hip/hip_runtime.h>

// Fused attention block (b=2, n=2048, dim=256, heads=8, inner=16384, d_head=2048)
// LOW-RANK: S_h = xn M_h xn^T (M_h = Wq_h^T Wk_h), Zt_h = N_h xn^T (N_h = Wo_h Wv_h).
// FLASH-FUSED: S -> exp -> PV in ONE kernel; the 134 MB E tensor never exists.
// Per block (i-tile 128, h, b): loop 16 j-tiles: S-tile = Y_h xn^T (gemm_bt K-loop,
// K=256) ; exp in-register + row-sum partials ; P -> LDS (pad 136) C-layout ->
// A-layout ; out_acc += P Zt^T (K=128/tile). End: reduce l, scale 1/l, fp32
// atomicAdd into out (sum over heads).  No softmax kernel, no E read/write.
// Pre-GEMMs: Mt_h=(Wq_h^T Wk_h)^T and N_h via split-K fp32-atomic GEMMs + cast;
// Y = xn Mt^T ; Zt = N xn^T.  All B^T-form, m97 recipe (128x128, BK=32,
// mfma_f32_16x16x32_bf16, global_load_lds w=16).

typedef unsigned short u16;
typedef unsigned int u32;
typedef __bf16 bf16x8 __attribute__((ext_vector_type(8)));
typedef float f32x4 __attribute__((ext_vector_type(4)));

__device__ __forceinline__ u16 f2bf(float f) {
    u32 u = __builtin_bit_cast(u32, f);
    u += 0x7fffu + ((u >> 16) & 1u);   // RNE; inputs finite
    return (u16)(u >> 16);
}

#define GLDS16(G, L)                                                                  \
    __builtin_amdgcn_global_load_lds((const __attribute__((address_space(1))) u32*)(G), \
                                     (__attribute__((address_space(3))) u32*)(L), 16, 0, 0)

// ---------------------------------------------------------------------------
// B^T GEMM: C[m,n] (+)= sum_k A[m,k]*B[n,k].  blockIdx.z = (kc*NB+zb)*H + zh.
// ---------------------------------------------------------------------------
template <typename OutT, bool ATOMIC>
__global__ void __launch_bounds__(256, 4) gemm_bt(
    const u16* __restrict__ A, const u16* __restrict__ B, OutT* __restrict__ C,
    int K, int lda, int ldb, int ldc,
    long sAh, long sAb, long sBh, long sBb, long sCh, long sCb,
    int H, int NB, long ksA, long ksB)
{
    __shared__ u16 ldsA[128 * 32];
    __shared__ u16 ldsB[128 * 32];

    const int z = blockIdx.z;
    const int zh = z % H;
    const int zq = z / H;
    const int zb = zq % NB;
    const int kc = zq / NB;
    A += (size_t)zh * sAh + (size_t)zb * sAb + (size_t)kc * ksA;
    B += (size_t)zh * sBh + (size_t)zb * sBb + (size_t)kc * ksB;
    C += (size_t)zh * sCh + (size_t)zb * sCb;

    const int bm = blockIdx.y * 128;
    const int bn = blockIdx.x * 128;
    const int t = threadIdx.x;
    const int w = t >> 6, l = t & 63;
    const int wm = w >> 1, wn = w & 1;
    const int lr = l & 15, lk = l >> 4;
    const int sw = lk ^ ((lr >> 1) & 3);

    const int m0 = t >> 2, s0 = t & 3;
    const int c0 = s0 ^ ((m0 >> 1) & 3);
    const int m1 = 64 + m0;
    const int c1 = s0 ^ ((m1 >> 1) & 3);

    const u16* gA0 = A + (size_t)(bm + m0) * lda + c0 * 8;
    const u16* gA1 = A + (size_t)(bm + m1) * lda + c1 * 8;
    const u16* gB0 = B + (size_t)(bn + m0) * ldb + c0 * 8;
    const u16* gB1 = B + (size_t)(bn + m1) * ldb + c1 * 8;
    u16* lA0 = &ldsA[(t & ~63) * 8];
    u16* lA1 = &ldsA[(256 + (t & ~63)) * 8];
    u16* lB0 = &ldsB[(t & ~63) * 8];
    u16* lB1 = &ldsB[(256 + (t & ~63)) * 8];

    f32x4 acc[4][4];
#pragma unroll
    for (int i = 0; i < 4; ++i)
#pragma unroll
        for (int j = 0; j < 4; ++j)
            acc[i][j] = f32x4{0.f, 0.f, 0.f, 0.f};

    const int nk = K >> 5;
    for (int kt = 0; kt < nk; ++kt) {
        __syncthreads();
        GLDS16(gA0, lA0); GLDS16(gA1, lA1);
        GLDS16(gB0, lB0); GLDS16(gB1, lB1);
        gA0 += 32; gA1 += 32; gB0 += 32; gB1 += 32;
        __syncthreads();

        bf16x8 av[4], bv[4];
#pragma unroll
        for (int i = 0; i < 4; ++i) {
            av[i] = *(const bf16x8*)&ldsA[(wm * 64 + i * 16 + lr) * 32 + sw * 8];
            bv[i] = *(const bf16x8*)&ldsB[(wn * 64 + i * 16 + lr) * 32 + sw * 8];
        }
#pragma unroll
        for (int i = 0; i < 4; ++i)
#pragma unroll
            for (int j = 0; j < 4; ++j)
                acc[i][j] = __builtin_amdgcn_mfma_f32_16x16x32_bf16(av[i], bv[j], acc[i][j], 0, 0, 0);
    }

    // C/D layout: col = lane&15, row = (lane>>4)*4 + reg
#pragma unroll
    for (int i = 0; i < 4; ++i) {
        const int row0 = bm + wm * 64 + i * 16 + lk * 4;
#pragma unroll
        for (int j = 0; j < 4; ++j) {
            const int col = bn + wn * 64 + j * 16 + lr;
#pragma unroll
            for (int r = 0; r < 4; ++r) {
                const size_t idx = (size_t)(row0 + r) * ldc + col;
                const float v = acc[i][j][r];
                if constexpr (ATOMIC) {
                    atomicAdd(&C[idx], v);
                } else if constexpr (sizeof(OutT) == 2) {
                    C[idx] = (OutT)f2bf(v);
                } else {
                    C[idx] = (OutT)v;
                }
            }
        }
    }
}

// ---------------------------------------------------------------------------
// Flash-fused attention core.  Grid (16 i-tiles, 16 hb).  Block 256.
// Y  : [4096][2048]  row b*2048+i, col h*256+a   (SCALE folded)
// xn : [4096][256]
// Zt : [2][2048][2048]  row h*256+d', col j  (per-batch slice)
// out: [4096][256] fp32, atomic (sum over heads)
// ---------------------------------------------------------------------------
__global__ void __launch_bounds__(256, 1) attn_fused(
    const u16* __restrict__ Y, const u16* __restrict__ xn,
    const u16* __restrict__ Zt, float* __restrict__ out)
{
    __shared__ u16 ldsA[128 * 32];     // Y-tile staging
    __shared__ u16 ldsB[128 * 32];     // xn-tile staging
    __shared__ u16 ldsZ[256 * 32];     // Zt-tile staging
    __shared__ u16 Pl[128 * 136];      // P tile, padded (+8) for conflict-free A-reads
    __shared__ float l_lds[128];

    const int i0 = blockIdx.x * 128;
    const int hb = blockIdx.y;
    const int h = hb >> 1, b = hb & 1;

    const int t = threadIdx.x;
    const int w = t >> 6, l = t & 63;
    const int wm = w >> 1, wn = w & 1;
    const int lr = l & 15, lk = l >> 4;
    const int sw = lk ^ ((lr >> 1) & 3);

    if (t < 128) l_lds[t] = 0.f;

    // S-phase staging roles (A: Y rows i0+m, cols h*256+..; B: xn rows j0+m)
    const int m0 = t >> 2, s0 = t & 3;
    const int c0 = s0 ^ ((m0 >> 1) & 3);
    const int m1 = 64 + m0;
    const int c1 = s0 ^ ((m1 >> 1) & 3);

    const u16* gA0 = Y + (size_t)(b * 2048 + i0 + m0) * 2048 + h * 256 + c0 * 8;
    const u16* gA1 = Y + (size_t)(b * 2048 + i0 + m1) * 2048 + h * 256 + c1 * 8;
    const u16* gB0 = xn + (size_t)(b * 2048 + m0) * 256 + c0 * 8;
    const u16* gB1 = xn + (size_t)(b * 2048 + m1) * 256 + c1 * 8;
    u16* lA0 = &ldsA[(t & ~63) * 8];
    u16* lA1 = &ldsA[(256 + (t & ~63)) * 8];
    u16* lB0 = &ldsB[(t & ~63) * 8];
    u16* lB1 = &ldsB[(256 + (t & ~63)) * 8];

    // PV staging roles: 256x32 Zt tile, 4 chunks (16B) per thread
    const u16* Zb = Zt + (size_t)b * 4194304 + (size_t)h * 256 * 2048;
    const u16* gZ0; const u16* gZ1; const u16* gZ2; const u16* gZ3;
    u16 *lZ0, *lZ1, *lZ2, *lZ3;
    {
        const int q0 = t, q1 = 256 + t, q2 = 512 + t, q3 = 768 + t;
        const int mz0 = q0 >> 2, mz1 = q1 >> 2, mz2 = q2 >> 2, mz3 = q3 >> 2;
        const int cz0 = (q0 & 3) ^ ((mz0 >> 1) & 3);
        const int cz1 = (q1 & 3) ^ ((mz1 >> 1) & 3);
        const int cz2 = (q2 & 3) ^ ((mz2 >> 1) & 3);
        const int cz3 = (q3 & 3) ^ ((mz3 >> 1) & 3);
        gZ0 = Zb + (size_t)mz0 * 2048 + cz0 * 8;
        gZ1 = Zb + (size_t)mz1 * 2048 + cz1 * 8;
        gZ2 = Zb + (size_t)mz2 * 2048 + cz2 * 8;
        gZ3 = Zb + (size_t)mz3 * 2048 + cz3 * 8;
        lZ0 = &ldsZ[(t & ~63) * 8];
        lZ1 = &ldsZ[(256 + (t & ~63)) * 8];
        lZ2 = &ldsZ[(512 + (t & ~63)) * 8];
        lZ3 = &ldsZ[(768 + (t & ~63)) * 8];
    }

    f32x4 acc_o[4][8];
#pragma unroll
    for (int i = 0; i < 4; ++i)
#pragma unroll
        for (int j = 0; j < 8; ++j)
            acc_o[i][j] = f32x4{0.f, 0.f, 0.f, 0.f};
    float lsum[16];
#pragma unroll
    for (int i = 0; i < 16; ++i) lsum[i] = 0.f;

    for (int jt = 0; jt < 16; ++jt) {
        const int j0 = jt * 128;

        // ---- S phase: acc_s = Y_h[i-tile] . xn[j-tile]^T  (K=256) ----
        f32x4 acc_s[4][4];
#pragma unroll
        for (int i = 0; i < 4; ++i)
#pragma unroll
            for (int j = 0; j < 4; ++j)
                acc_s[i][j] = f32x4{0.f, 0.f, 0.f, 0.f};

#pragma unroll
        for (int kt = 0; kt < 8; ++kt) {
            __syncthreads();
            GLDS16(gA0 + kt * 32, lA0);
            GLDS16(gA1 + kt * 32, lA1);
            GLDS16(gB0 + (size_t)j0 * 256 + kt * 32, lB0);
            GLDS16(gB1 + (size_t)j0 * 256 + kt * 32, lB1);
            __syncthreads();
            bf16x8 av[4], bv[4];
#pragma unroll
            for (int i = 0; i < 4; ++i) {
                av[i] = *(const bf16x8*)&ldsA[(wm * 64 + i * 16 + lr) * 32 + sw * 8];
                bv[i] = *(const bf16x8*)&ldsB[(wn * 64 + i * 16 + lr) * 32 + sw * 8];
            }
#pragma unroll
            for (int i = 0; i < 4; ++i)
#pragma unroll
                for (int j = 0; j < 4; ++j)
                    acc_s[i][j] = __builtin_amdgcn_mfma_f32_16x16x32_bf16(av[i], bv[j], acc_s[i][j], 0, 0, 0);
        }

        // ---- exp + row-sum partials + P -> LDS (C-layout -> [i][j]) ----
#pragma unroll
        for (int i = 0; i < 4; ++i)
#pragma unroll
            for (int j = 0; j < 4; ++j)
#pragma unroll
                for (int r = 0; r < 4; ++r) {
                    const float e = __expf(acc_s[i][j][r]);
                    lsum[i * 4 + r] += e;
                    Pl[(wm * 64 + i * 16 + lk * 4 + r) * 136 + wn * 64 + j * 16 + lr] = f2bf(e);
                }

        // ---- PV phase: acc_o += P . Zt-tile^T  (K=128, BK=32) ----
#pragma unroll
        for (int kt = 0; kt < 4; ++kt) {
            __syncthreads();                    // P visible (kt=0) + ldsZ safe
            GLDS16(gZ0 + j0 + kt * 32, lZ0);
            GLDS16(gZ1 + j0 + kt * 32, lZ1);
            GLDS16(gZ2 + j0 + kt * 32, lZ2);
            GLDS16(gZ3 + j0 + kt * 32, lZ3);
            __syncthreads();
            bf16x8 av[4], bv[8];
#pragma unroll
            for (int i = 0; i < 4; ++i)
                av[i] = *(const bf16x8*)&Pl[(wm * 64 + i * 16 + lr) * 136 + kt * 32 + lk * 8];
#pragma unroll
            for (int j = 0; j < 8; ++j)
                bv[j] = *(const bf16x8*)&ldsZ[(wn * 128 + j * 16 + lr) * 32 + sw * 8];
#pragma unroll
            for (int i = 0; i < 4; ++i)
#pragma unroll
                for (int j = 0; j < 8; ++j)
                    acc_o[i][j] = __builtin_amdgcn_mfma_f32_16x16x32_bf16(av[i], bv[j], acc_o[i][j], 0, 0, 0);
        }
    }

    // ---- finalize l: butterfly over 16-lane group, cross-wave LDS add ----
#pragma unroll
    for (int i = 0; i < 4; ++i)
#pragma unroll
        for (int r = 0; r < 4; ++r) {
            float s = lsum[i * 4 + r];
            s += __shfl_xor(s, 1, 64);
            s += __shfl_xor(s, 2, 64);
            s += __shfl_xor(s, 4, 64);
            s += __shfl_xor(s, 8, 64);
            if (lr == 0) atomicAdd(&l_lds[wm * 64 + i * 16 + lk * 4 + r], s);
        }
    __syncthreads();

    // ---- scale by 1/l, atomic-accumulate into out (sum over heads) ----
#pragma unroll
    for (int i = 0; i < 4; ++i)
#pragma unroll
        for (int r = 0; r < 4; ++r) {
            const int row = wm * 64 + i * 16 + lk * 4 + r;
            const float rl = 1.0f / l_lds[row];
            float* orow = out + (size_t)(b * 2048 + i0 + row) * 256 + wn * 128;
#pragma unroll
            for (int j = 0; j < 8; ++j)
                atomicAdd(&orow[j * 16 + lr], acc_o[i][j][r] * rl);
        }
}

// ---------------------------------------------------------------------------
// Transposed cast: src fp32 [8][2048][256] -> dst bf16 [8][256][2048].
// ---------------------------------------------------------------------------
__global__ void __launch_bounds__(256) tcast_kernel(const float* __restrict__ src,
                                                    u16* __restrict__ dst, float scale)
{
    __shared__ u16 tile[64][66];
    const int h = blockIdx.z;
    const int d0 = blockIdx.x * 64;
    const int a0 = blockIdx.y * 64;
    const int t = threadIdx.x;
    const int c = t & 63, r0 = t >> 6;
#pragma unroll
    for (int rr = 0; rr < 16; ++rr) {
        const int r = r0 + rr * 4;
        tile[r][c] = f2bf(src[((size_t)h * 2048 + d0 + r) * 256 + a0 + c] * scale);
    }
    __syncthreads();
#pragma unroll
    for (int rr = 0; rr < 16; ++rr) {
        const int r = r0 + rr * 4;
        dst[((size_t)h * 256 + a0 + r) * 2048 + d0 + c] = tile[c][r];
    }
}

__global__ void __launch_bounds__(64) ln_kernel(const float* __restrict__ x,
                                                const float* __restrict__ g,
                                                u16* __restrict__ xn)
{
    const size_t row = blockIdx.x;
    const int l = threadIdx.x;
    const float4 v = ((const float4*)(x + row * 256))[l];
    float s = v.x + v.y + v.z + v.w;
    float q = v.x * v.x + v.y * v.y + v.z * v.z + v.w * v.w;
#pragma unroll
    for (int o = 32; o > 0; o >>= 1) {
        s += __shfl_xor(s, o, 64);
        q += __shfl_xor(q, o, 64);
    }
    const float mu = s * (1.0f / 256.0f);
    const float var = q * (1.0f / 256.0f) - mu * mu;
    const float rs = rsqrtf(var + 1e-5f);
    const float4 gg = ((const float4*)g)[l];
    ushort4 o4;
    o4.x = f2bf((v.x - mu) * rs * (gg.x + 1.0f));
    o4.y = f2bf((v.y - mu) * rs * (gg.y + 1.0f));
    o4.z = f2bf((v.z - mu) * rs * (gg.z + 1.0f));
    o4.w = f2bf((v.w - mu) * rs * (gg.w + 1.0f));
    ((ushort4*)(xn + row * 256))[l] = o4;
}

__global__ void __launch_bounds__(256) cast_bf16_kernel(const float* __restrict__ src,
                                                        u16* __restrict__ dst, float scale)
{
    const size_t i = (size_t)blockIdx.x * 256 + threadIdx.x;
    const float4 v = ((const float4*)src)[i];
    ushort4 o4;
    o4.x = f2bf(v.x * scale);
    o4.y = f2bf(v.y * scale);
    o4.z = f2bf(v.z * scale);
    o4.w = f2bf(v.w * scale);
    ((ushort4*)dst)[i] = o4;
}

extern "C" void kernel_launch(void* const* d_in, const int* in_sizes, int n_in,
                              void* d_out, int out_size, void* d_ws, size_t ws_size,
                              hipStream_t stream)
{
    (void)in_sizes; (void)n_in; (void)ws_size;
    const float* x     = (const float*)d_in[0];
    const float* gamma = (const float*)d_in[1];
    const float* Wq    = (const float*)d_in[2];
    const float* Wk    = (const float*)d_in[3];
    const float* Wv    = (const float*)d_in[4];
    const float* Wo    = (const float*)d_in[5];
    float* out = (float*)d_out;

    char* ws = (char*)d_ws;
    const size_t MB = 1048576;
    u16* wqt   = (u16*)(ws);             // [8][256][2048] bf16 (SCALE folded)
    u16* wkt   = (u16*)(ws + 8 * MB);
    u16* wvt   = (u16*)(ws + 16 * MB);
    u16* wo    = (u16*)(ws + 24 * MB);   // [256][16384] bf16
    u16* xn    = (u16*)(ws + 32 * MB);   // [4096][256] bf16
    u16* Mt    = (u16*)(ws + 34 * MB);   // [8*256][256] bf16 (Mt_h = M_h^T)
    u16* Nb    = (u16*)(ws + 35 * MB);   // [8*256][256] bf16
    float* MtF = (float*)(ws + 36 * MB); // fp32 split-K accum for Mt (2 MB)
    float* NbF = (float*)(ws + 40 * MB); // fp32 split-K accum for Nb (2 MB)
    u16* Y     = (u16*)(ws + 44 * MB);   // [4096][2048] bf16
    u16* Zt    = (u16*)(ws + 60 * MB);   // [2][2048][2048] bf16

    hipMemsetAsync(d_out, 0, (size_t)out_size * sizeof(float), stream);
    hipMemsetAsync(MtF, 0, 4 * MB, stream);     // MtF + NbF (contiguous 8 MB? no: 2+2 at 36,40)
    hipMemsetAsync(NbF, 0, 4 * MB, stream);

    tcast_kernel<<<dim3(32, 4, 8), 256, 0, stream>>>(Wq, wqt, 0.125f);
    tcast_kernel<<<dim3(32, 4, 8), 256, 0, stream>>>(Wk, wkt, 1.0f);
    tcast_kernel<<<dim3(32, 4, 8), 256, 0, stream>>>(Wv, wvt, 1.0f);
    cast_bf16_kernel<<<4096, 256, 0, stream>>>(Wo, wo, 1.0f);
    ln_kernel<<<4096, 64, 0, stream>>>(x, gamma, xn);

    // Mt_h[a,c] = sum_e wkt_h[a,e]*wqt_h[c,e] : split-K x4 (K-chunk 512), fp32 atomic
    gemm_bt<float, true><<<dim3(2, 2, 32), 256, 0, stream>>>(
        wkt, wqt, MtF, 512, 2048, 2048, 256,
        524288L, 0, 524288L, 0, 65536L, 0, 8, 1, 512L, 512L);

    // N_h[d',a] = sum_e Wo[d',h*2048+e]*wvt_h[a,e] : split-K x4, fp32 atomic
    gemm_bt<float, true><<<dim3(2, 2, 32), 256, 0, stream>>>(
        wo, wvt, NbF, 512, 16384, 2048, 256,
        2048L, 0, 524288L, 0, 65536L, 0, 8, 1, 512L, 512L);

    // cast MtF -> Mt (1 MB bf16), NbF -> Nb
    cast_bf16_kernel<<<512, 256, 0, stream>>>(MtF, Mt, 1.0f);
    cast_bf16_kernel<<<512, 256, 0, stream>>>(NbF, Nb, 1.0f);

    // Y[t, h*256+a] = sum_c xn[t,c] * Mt[h*256+a, c]
    gemm_bt<u16, false><<<dim3(16, 32, 1), 256, 0, stream>>>(
        xn, Mt, Y, 256, 256, 256, 2048,
        0, 0, 0, 0, 0, 0, 1, 1, 0, 0);

    // Zt[b][h*256+d', j] = sum_a Nb[h*256+d', a] * xn[b*2048+j, a]
    gemm_bt<u16, false><<<dim3(16, 16, 2), 256, 0, stream>>>(
        Nb, xn, Zt, 256, 256, 256, 2048,
        0, 0, 0, 524288L, 0, 4194304L, 1, 2, 0, 0);

    // fused S -> softmax -> PV -> head-sum
    attn_fused<<<dim3(16, 16), 256, 0, stream>>>(Y, xn, Zt, out);
}